// Round 2
// baseline (2608.409 us; speedup 1.0000x reference)
//
#include <hip/hip_runtime.h>
#include <hip/hip_bf16.h>

typedef __attribute__((ext_vector_type(4))) float f32x4;
typedef __attribute__((ext_vector_type(16))) float f32x16;
typedef __attribute__((ext_vector_type(8))) short s16x8;
typedef unsigned short ushort_t;

// Sizes: B=4, H=W=64 -> N=4096, C=512, GROUPS=32 (cg=16)
#define N_DIM 4096
#define C_DIM 512

static __device__ __forceinline__ unsigned short f2bf(float f) {
    union { float f; unsigned u; } v; v.f = f;
    unsigned r = v.u + 0x7FFFu + ((v.u >> 16) & 1u);
    return (unsigned short)(r >> 16);
}
static __device__ __forceinline__ unsigned pkbf(float a, float b) {
    return (unsigned)f2bf(a) | ((unsigned)f2bf(b) << 16);
}

// ---------------- GroupNorm stats: one block per (b,g), reduce 4096*16 elems
__global__ void gn_stats_kernel(const float* __restrict__ x, float* __restrict__ stats) {
    int bg = blockIdx.x;
    int b = bg >> 5, g = bg & 31;
    const float* base = x + (size_t)b * (N_DIM * C_DIM) + g * 16;
    float sum = 0.f, ss = 0.f;
    for (int n = threadIdx.x; n < N_DIM; n += 256) {
        const float4* p = (const float4*)(base + (size_t)n * C_DIM);
        #pragma unroll
        for (int t = 0; t < 4; ++t) {
            float4 v = p[t];
            sum += v.x + v.y + v.z + v.w;
            ss  += v.x*v.x + v.y*v.y + v.z*v.z + v.w*v.w;
        }
    }
    #pragma unroll
    for (int o = 32; o > 0; o >>= 1) {
        sum += __shfl_down(sum, o);
        ss  += __shfl_down(ss, o);
    }
    __shared__ float red[8];
    int wid = threadIdx.x >> 6, lane = threadIdx.x & 63;
    if (lane == 0) { red[wid*2] = sum; red[wid*2+1] = ss; }
    __syncthreads();
    if (threadIdx.x == 0) {
        sum = red[0]+red[2]+red[4]+red[6];
        ss  = red[1]+red[3]+red[5]+red[7];
        float mean = sum * (1.f/65536.f);
        float var  = ss  * (1.f/65536.f) - mean*mean;
        stats[bg*2]   = mean;
        stats[bg*2+1] = rsqrtf(var + 1e-5f);
    }
}

// ---------------- normalize + gamma/beta + cast to bf16
__global__ void gn_norm_kernel(const float* __restrict__ x, const float* __restrict__ gamma,
                               const float* __restrict__ beta, const float* __restrict__ stats,
                               ushort_t* __restrict__ xn) {
    size_t i = ((size_t)blockIdx.x * 256 + threadIdx.x) * 4;
    int c = (int)(i & 511);
    int b = (int)(i >> 21);
    int bg = b*32 + (c >> 4);
    float mean = stats[bg*2], rstd = stats[bg*2+1];
    float4 v  = *(const float4*)(x + i);
    float4 ga = *(const float4*)(gamma + c);
    float4 be = *(const float4*)(beta + c);
    ushort4 o;
    o.x = f2bf((v.x - mean) * rstd * ga.x + be.x);
    o.y = f2bf((v.y - mean) * rstd * ga.y + be.y);
    o.z = f2bf((v.z - mean) * rstd * ga.z + be.z);
    o.w = f2bf((v.w - mean) * rstd * ga.w + be.w);
    *(ushort4*)(xn + i) = o;
}

// ---------------- weights: fp32 [Cin][Cout] -> bf16 transposed [Cout][Cin], 4 mats
__global__ void wconv_kernel(const float* __restrict__ wq, const float* __restrict__ wk,
                             const float* __restrict__ wv, const float* __restrict__ wp,
                             ushort_t* __restrict__ wt) {
    int idx = blockIdx.x * 256 + threadIdx.x;
    int m = idx >> 18;
    int r = idx & 262143;
    int ci = r >> 9, co = r & 511;
    const float* w = (m == 0) ? wq : (m == 1) ? wk : (m == 2) ? wv : wp;
    wt[(size_t)m * 262144 + (size_t)co * 512 + ci] = f2bf(w[(size_t)ci * 512 + co]);
}

// ---------------- QKV GEMM: xn[16384,512] @ Wt -> q,k (row-major, q pre-scaled), v (transposed per batch)
__global__ __launch_bounds__(256) void qkv_kernel(const ushort_t* __restrict__ xn, const ushort_t* __restrict__ wt,
                         const float* __restrict__ bq, const float* __restrict__ bk, const float* __restrict__ bv,
                         ushort_t* __restrict__ q, ushort_t* __restrict__ k, ushort_t* __restrict__ v) {
    int z = blockIdx.z;
    const ushort_t* W = wt + (size_t)z * 262144;
    const float* bias = (z == 0) ? bq : (z == 1) ? bk : bv;
    float scale = (z == 0) ? 0.04419417382415922f : 1.0f;  // 512^-0.5 folded into q
    int wid = threadIdx.x >> 6, lane = threadIdx.x & 63;
    int lr = lane & 15, lg = lane >> 4;
    int r0 = blockIdx.x * 64 + wid * 16;
    int c0 = blockIdx.y * 64;
    const ushort_t* arow = xn + (size_t)(r0 + lr) * 512 + lg * 8;
    f32x4 acc[4] = {};
    for (int k0 = 0; k0 < 512; k0 += 32) {
        s16x8 af = *(const s16x8*)(arow + k0);
        #pragma unroll
        for (int ct = 0; ct < 4; ++ct) {
            s16x8 bf = *(const s16x8*)(W + (size_t)(c0 + ct*16 + lr) * 512 + k0 + lg * 8);
            acc[ct] = __builtin_amdgcn_mfma_f32_16x16x32_bf16(af, bf, acc[ct], 0, 0, 0);
        }
    }
    if (z < 2) {
        ushort_t* out = (z == 0) ? q : k;
        #pragma unroll
        for (int ct = 0; ct < 4; ++ct) {
            int cg = c0 + ct*16 + lr;
            float bb = bias[cg];
            #pragma unroll
            for (int r2 = 0; r2 < 4; ++r2) {
                int row = r0 + lg*4 + r2;
                out[(size_t)row * 512 + cg] = f2bf((acc[ct][r2] + bb) * scale);
            }
        }
    } else {
        #pragma unroll
        for (int ct = 0; ct < 4; ++ct) {
            int cg = c0 + ct*16 + lr;
            float bb = bias[cg];
            int row = r0 + lg*4;
            int batch = row >> 12, j = row & 4095;
            ushort4 o;
            o.x = f2bf(acc[ct][0] + bb);
            o.y = f2bf(acc[ct][1] + bb);
            o.z = f2bf(acc[ct][2] + bb);
            o.w = f2bf(acc[ct][3] + bb);
            *(ushort4*)(v + (size_t)batch * (512*4096) + (size_t)cg * 4096 + j) = o;
        }
    }
}

// ---------------- flash attention, 32x32x16 MFMA, 2 waves x 32 q-rows, KVBLK=32,
// double-buffered LDS staged via global_load_lds with pre-swizzled source (rule 21),
// counted vmcnt(32) pipeline (T3/T4), swapped QK^T -> lane-local softmax, T12 repack, T13 defer-max.
__global__ __launch_bounds__(128, 1) void attn_kernel(const ushort_t* __restrict__ q, const ushort_t* __restrict__ k,
                          const ushort_t* __restrict__ vt, ushort_t* __restrict__ O) {
    __shared__ char slds[131072];   // 2 bufs x (K tile 32KB + V tile 32KB)
    const int tid  = threadIdx.x;
    const int w    = tid >> 6;       // wave 0 stages K, wave 1 stages V
    const int lane = tid & 63;
    const int l31  = lane & 31;
    const int h    = lane >> 5;
    const int batch = blockIdx.y;
    const int i0 = blockIdx.x * 64 + w * 32;
    const char* kb = (const char*)(k  + (size_t)batch * (4096 * 512));
    const char* vb = (const char*)(vt + (size_t)batch * (512 * 4096));
    const ushort_t* qb = q + (size_t)batch * (4096 * 512);

    // V-staging per-lane constants: granule g = p*64+lane -> c = p*16 + (lane>>2), lds slot = lane&3,
    // holds global slot s = (lane&3) ^ (c&3)
    const int vcrow = lane >> 2;
    const int vscol = ((lane & 3) ^ (vcrow & 3)) << 4;

    // Q fragments: lane holds Q[i0 + l31][16*kk + 8*h .. +8]  (B-operand of mfma(K,Q))
    s16x8 qf[32];
    {
        const ushort_t* qrow = qb + (size_t)(i0 + l31) * 512 + h * 8;
        #pragma unroll
        for (int kk = 0; kk < 32; ++kk) qf[kk] = *(const s16x8*)(qrow + kk * 16);
    }

    f32x16 acc[16];
    #pragma unroll
    for (int t = 0; t < 16; ++t) acc[t] = (f32x16){};
    float mrun = -1e30f, srun = 0.f;

    auto STAGE = [&](int buf, int j0s) {
        char* lb = slds + buf * 65536 + w * 32768;
        if (w == 0) {
            // K tile rows j0s..+31: row j at lds row p=j-j0s; lds slot6=lane holds global slot lane^(p&7)
            const char* g = kb + (size_t)j0s * 1024;
            #pragma unroll
            for (int p = 0; p < 32; ++p) {
                const char* src = g + p * 1024 + ((lane ^ (p & 7)) << 4);
                __builtin_amdgcn_global_load_lds((const __attribute__((address_space(1))) void*)src,
                                                 (__attribute__((address_space(3))) void*)(lb + p * 1024), 16, 0, 0);
            }
        } else {
            // V^T tile cols j0s..+31 (64B per c-row)
            const char* g = vb + (size_t)j0s * 2 + (size_t)vcrow * 8192 + vscol;
            #pragma unroll
            for (int p = 0; p < 32; ++p) {
                __builtin_amdgcn_global_load_lds((const __attribute__((address_space(1))) void*)(g + (size_t)p * 131072),
                                                 (__attribute__((address_space(3))) void*)(lb + p * 1024), 16, 0, 0);
            }
        }
    };

    STAGE(0, 0);

    for (int t = 0; t < 128; ++t) {
        const int cur = t & 1;
        if (t < 127) {
            STAGE(cur ^ 1, (t + 1) * 32);
            asm volatile("s_waitcnt vmcnt(32)" ::: "memory");
        } else {
            asm volatile("s_waitcnt vmcnt(0)" ::: "memory");
        }
        __builtin_amdgcn_s_barrier();
        asm volatile("" ::: "memory");

        const char* kl = slds + cur * 65536;
        const char* vl = kl + 32768;

        // S^T[j 32][i 32] = K_tile(A) . Q^T(B), two accumulation chains
        f32x16 sa = {}, sb = {};
        #pragma unroll
        for (int kk = 0; kk < 32; kk += 2) {
            s16x8 kf0 = *(const s16x8*)(kl + l31 * 1024 + ((((kk    ) << 1) + h) ^ (lane & 7)) * 16);
            s16x8 kf1 = *(const s16x8*)(kl + l31 * 1024 + ((((kk + 1) << 1) + h) ^ (lane & 7)) * 16);
            sa = __builtin_amdgcn_mfma_f32_32x32x16_bf16(kf0, qf[kk],     sa, 0, 0, 0);
            sb = __builtin_amdgcn_mfma_f32_32x32x16_bf16(kf1, qf[kk + 1], sb, 0, 0, 0);
        }
        f32x16 st = sa + sb;  // reg r: S^T[j = (r&3)+8*(r>>2)+4*h][i = i0+l31]

        // online softmax per q-column i (16 regs + partner half via xor-32)
        float tm = st[0];
        #pragma unroll
        for (int r = 1; r < 16; ++r) tm = fmaxf(tm, st[r]);
        tm = fmaxf(tm, __shfl_xor(tm, 32));
        if (!__all(tm <= mrun + 8.f)) {       // T13 defer-max, THR=8
            float mn = fmaxf(mrun, tm);
            float rs = __expf(mrun - mn);
            #pragma unroll
            for (int c = 0; c < 16; ++c) acc[c] *= rs;
            srun *= rs;
            mrun = mn;
        }
        f32x16 p;
        #pragma unroll
        for (int r = 0; r < 16; ++r) p[r] = __expf(st[r] - mrun);
        float ts = p[0];
        #pragma unroll
        for (int r = 1; r < 16; ++r) ts += p[r];
        srun += ts + __shfl_xor(ts, 32);

        // repack P^T -> PV B-fragments (T12 structure, shfl_xor32 exchange)
        unsigned u0 = pkbf(p[0],  p[1]),  v0 = pkbf(p[2],  p[3]);
        unsigned u1 = pkbf(p[4],  p[5]),  v1 = pkbf(p[6],  p[7]);
        unsigned u2 = pkbf(p[8],  p[9]),  v2 = pkbf(p[10], p[11]);
        unsigned u3 = pkbf(p[12], p[13]), v3 = pkbf(p[14], p[15]);
        unsigned xu0 = (unsigned)__shfl_xor((int)(h ? u0 : u1), 32);
        unsigned xv0 = (unsigned)__shfl_xor((int)(h ? v0 : v1), 32);
        unsigned xu1 = (unsigned)__shfl_xor((int)(h ? u2 : u3), 32);
        unsigned xv1 = (unsigned)__shfl_xor((int)(h ? v2 : v3), 32);
        union { unsigned u[4]; s16x8 v; } pf0u, pf1u;
        pf0u.u[0] = h ? xu0 : u0;  pf0u.u[1] = h ? xv0 : v0;
        pf0u.u[2] = h ? u1  : xu0; pf0u.u[3] = h ? v1  : xv0;
        pf1u.u[0] = h ? xu1 : u2;  pf1u.u[1] = h ? xv1 : v2;
        pf1u.u[2] = h ? u3  : xu1; pf1u.u[3] = h ? v3  : xv1;
        s16x8 pf0 = pf0u.v, pf1 = pf1u.v;

        // O^T[c][i] += V^T_tile(A) . P^T(B)
        #pragma unroll
        for (int ct = 0; ct < 16; ++ct) {
            const char* vrow = vl + (ct * 32 + l31) * 64;
            s16x8 vf0 = *(const s16x8*)(vrow + ((( h    ) ^ (lane & 3)) << 4));
            s16x8 vf1 = *(const s16x8*)(vrow + (((2 | h) ^ (lane & 3)) << 4));
            acc[ct] = __builtin_amdgcn_mfma_f32_32x32x16_bf16(vf0, pf0, acc[ct], 0, 0, 0);
            acc[ct] = __builtin_amdgcn_mfma_f32_32x32x16_bf16(vf1, pf1, acc[ct], 0, 0, 0);
        }
        asm volatile("" ::: "memory");
        __builtin_amdgcn_s_barrier();
    }

    float inv = 1.f / srun;
    ushort_t* orow = O + (size_t)batch * (4096 * 512) + (size_t)(i0 + l31) * 512;
    #pragma unroll
    for (int ct = 0; ct < 16; ++ct) {
        #pragma unroll
        for (int g2 = 0; g2 < 4; ++g2) {
            ushort4 o;
            o.x = f2bf(acc[ct][g2 * 4 + 0] * inv);
            o.y = f2bf(acc[ct][g2 * 4 + 1] * inv);
            o.z = f2bf(acc[ct][g2 * 4 + 2] * inv);
            o.w = f2bf(acc[ct][g2 * 4 + 3] * inv);
            *(ushort4*)(orow + ct * 32 + g2 * 8 + h * 4) = o;
        }
    }
}

// ---------------- final projection + bias + residual (fp32 out)
__global__ __launch_bounds__(256) void proj_kernel(const ushort_t* __restrict__ O, const ushort_t* __restrict__ wt,
                          const float* __restrict__ bp, const float* __restrict__ x, float* __restrict__ out) {
    int wid = threadIdx.x >> 6, lane = threadIdx.x & 63;
    int lr = lane & 15, lg = lane >> 4;
    int r0 = blockIdx.x * 64 + wid * 16;
    int c0 = blockIdx.y * 64;
    const ushort_t* W = wt + (size_t)3 * 262144;
    const ushort_t* arow = O + (size_t)(r0 + lr) * 512 + lg * 8;
    f32x4 acc[4] = {};
    for (int k0 = 0; k0 < 512; k0 += 32) {
        s16x8 af = *(const s16x8*)(arow + k0);
        #pragma unroll
        for (int ct = 0; ct < 4; ++ct) {
            s16x8 bf = *(const s16x8*)(W + (size_t)(c0 + ct*16 + lr) * 512 + k0 + lg * 8);
            acc[ct] = __builtin_amdgcn_mfma_f32_16x16x32_bf16(af, bf, acc[ct], 0, 0, 0);
        }
    }
    #pragma unroll
    for (int ct = 0; ct < 4; ++ct) {
        int cg = c0 + ct*16 + lr;
        float bb = bp[cg];
        #pragma unroll
        for (int r2 = 0; r2 < 4; ++r2) {
            size_t idx = (size_t)(r0 + lg*4 + r2) * 512 + cg;
            out[idx] = acc[ct][r2] + bb + x[idx];
        }
    }
}

extern "C" void kernel_launch(void* const* d_in, const int* in_sizes, int n_in,
                              void* d_out, int out_size, void* d_ws, size_t ws_size,
                              hipStream_t stream) {
    (void)in_sizes; (void)n_in; (void)out_size; (void)ws_size;
    const float* x     = (const float*)d_in[0];
    const float* gamma = (const float*)d_in[1];
    const float* beta  = (const float*)d_in[2];
    const float* wq    = (const float*)d_in[3];
    const float* bq    = (const float*)d_in[4];
    const float* wk    = (const float*)d_in[5];
    const float* bk    = (const float*)d_in[6];
    const float* wv    = (const float*)d_in[7];
    const float* bv    = (const float*)d_in[8];
    const float* wp    = (const float*)d_in[9];
    const float* bp    = (const float*)d_in[10];
    float* out = (float*)d_out;

    char* ws = (char*)d_ws;
    ushort_t* wt   = (ushort_t*)(ws);                 // 2 MB  (4x 512x512 bf16, transposed)
    float*    stats= (float*)(ws + (2ull<<20));       // 1 KB
    ushort_t* xn   = (ushort_t*)(ws + (4ull<<20));    // 16 MB
    ushort_t* qb   = (ushort_t*)(ws + (20ull<<20));   // 16 MB (pre-scaled by C^-0.5)
    ushort_t* kb   = (ushort_t*)(ws + (36ull<<20));   // 16 MB
    ushort_t* vt   = (ushort_t*)(ws + (52ull<<20));   // 16 MB ([b][c][n] transposed)
    ushort_t* Ob   = (ushort_t*)(ws + (68ull<<20));   // 16 MB

    hipLaunchKernelGGL(wconv_kernel,    dim3(4096),       dim3(256), 0, stream, wq, wk, wv, wp, wt);
    hipLaunchKernelGGL(gn_stats_kernel, dim3(128),        dim3(256), 0, stream, x, stats);
    hipLaunchKernelGGL(gn_norm_kernel,  dim3(8192),       dim3(256), 0, stream, x, gamma, beta, stats, xn);
    hipLaunchKernelGGL(qkv_kernel,      dim3(256, 8, 3),  dim3(256), 0, stream, xn, wt, bq, bk, bv, qb, kb, vt);
    hipLaunchKernelGGL(attn_kernel,     dim3(64, 4),      dim3(128), 0, stream, qb, kb, vt, Ob);
    hipLaunchKernelGGL(proj_kernel,     dim3(256, 8),     dim3(256), 0, stream, Ob, wt, bp, x, out);
}

// Round 3
// 1094.956 us; speedup vs baseline: 2.3822x; 2.3822x over previous
//
#include <hip/hip_runtime.h>
#include <hip/hip_bf16.h>

typedef __attribute__((ext_vector_type(4))) float f32x4;
typedef __attribute__((ext_vector_type(16))) float f32x16;
typedef __attribute__((ext_vector_type(8))) short s16x8;
typedef unsigned short ushort_t;

// Sizes: B=4, H=W=64 -> N=4096, C=512, GROUPS=32 (cg=16)
#define N_DIM 4096
#define C_DIM 512

static __device__ __forceinline__ unsigned short f2bf(float f) {
    union { float f; unsigned u; } v; v.f = f;
    unsigned r = v.u + 0x7FFFu + ((v.u >> 16) & 1u);
    return (unsigned short)(r >> 16);
}
static __device__ __forceinline__ unsigned pkbf(float a, float b) {
    return (unsigned)f2bf(a) | ((unsigned)f2bf(b) << 16);
}

// ---------------- GroupNorm stats: one block per (b,g), reduce 4096*16 elems
__global__ void gn_stats_kernel(const float* __restrict__ x, float* __restrict__ stats) {
    int bg = blockIdx.x;
    int b = bg >> 5, g = bg & 31;
    const float* base = x + (size_t)b * (N_DIM * C_DIM) + g * 16;
    float sum = 0.f, ss = 0.f;
    for (int n = threadIdx.x; n < N_DIM; n += 256) {
        const float4* p = (const float4*)(base + (size_t)n * C_DIM);
        #pragma unroll
        for (int t = 0; t < 4; ++t) {
            float4 v = p[t];
            sum += v.x + v.y + v.z + v.w;
            ss  += v.x*v.x + v.y*v.y + v.z*v.z + v.w*v.w;
        }
    }
    #pragma unroll
    for (int o = 32; o > 0; o >>= 1) {
        sum += __shfl_down(sum, o);
        ss  += __shfl_down(ss, o);
    }
    __shared__ float red[8];
    int wid = threadIdx.x >> 6, lane = threadIdx.x & 63;
    if (lane == 0) { red[wid*2] = sum; red[wid*2+1] = ss; }
    __syncthreads();
    if (threadIdx.x == 0) {
        sum = red[0]+red[2]+red[4]+red[6];
        ss  = red[1]+red[3]+red[5]+red[7];
        float mean = sum * (1.f/65536.f);
        float var  = ss  * (1.f/65536.f) - mean*mean;
        stats[bg*2]   = mean;
        stats[bg*2+1] = rsqrtf(var + 1e-5f);
    }
}

// ---------------- normalize + gamma/beta + cast to bf16
__global__ void gn_norm_kernel(const float* __restrict__ x, const float* __restrict__ gamma,
                               const float* __restrict__ beta, const float* __restrict__ stats,
                               ushort_t* __restrict__ xn) {
    size_t i = ((size_t)blockIdx.x * 256 + threadIdx.x) * 4;
    int c = (int)(i & 511);
    int b = (int)(i >> 21);
    int bg = b*32 + (c >> 4);
    float mean = stats[bg*2], rstd = stats[bg*2+1];
    float4 v  = *(const float4*)(x + i);
    float4 ga = *(const float4*)(gamma + c);
    float4 be = *(const float4*)(beta + c);
    ushort4 o;
    o.x = f2bf((v.x - mean) * rstd * ga.x + be.x);
    o.y = f2bf((v.y - mean) * rstd * ga.y + be.y);
    o.z = f2bf((v.z - mean) * rstd * ga.z + be.z);
    o.w = f2bf((v.w - mean) * rstd * ga.w + be.w);
    *(ushort4*)(xn + i) = o;
}

// ---------------- weights: fp32 [Cin][Cout] -> bf16 transposed [Cout][Cin], 4 mats
__global__ void wconv_kernel(const float* __restrict__ wq, const float* __restrict__ wk,
                             const float* __restrict__ wv, const float* __restrict__ wp,
                             ushort_t* __restrict__ wt) {
    int idx = blockIdx.x * 256 + threadIdx.x;
    int m = idx >> 18;
    int r = idx & 262143;
    int ci = r >> 9, co = r & 511;
    const float* w = (m == 0) ? wq : (m == 1) ? wk : (m == 2) ? wv : wp;
    wt[(size_t)m * 262144 + (size_t)co * 512 + ci] = f2bf(w[(size_t)ci * 512 + co]);
}

// ---------------- QKV GEMM: xn[16384,512] @ Wt -> q,k (row-major, q pre-scaled), v (transposed per batch)
__global__ __launch_bounds__(256) void qkv_kernel(const ushort_t* __restrict__ xn, const ushort_t* __restrict__ wt,
                         const float* __restrict__ bq, const float* __restrict__ bk, const float* __restrict__ bv,
                         ushort_t* __restrict__ q, ushort_t* __restrict__ k, ushort_t* __restrict__ v) {
    int z = blockIdx.z;
    const ushort_t* W = wt + (size_t)z * 262144;
    const float* bias = (z == 0) ? bq : (z == 1) ? bk : bv;
    float scale = (z == 0) ? 0.04419417382415922f : 1.0f;  // 512^-0.5 folded into q
    int wid = threadIdx.x >> 6, lane = threadIdx.x & 63;
    int lr = lane & 15, lg = lane >> 4;
    int r0 = blockIdx.x * 64 + wid * 16;
    int c0 = blockIdx.y * 64;
    const ushort_t* arow = xn + (size_t)(r0 + lr) * 512 + lg * 8;
    f32x4 acc[4] = {};
    for (int k0 = 0; k0 < 512; k0 += 32) {
        s16x8 af = *(const s16x8*)(arow + k0);
        #pragma unroll
        for (int ct = 0; ct < 4; ++ct) {
            s16x8 bf = *(const s16x8*)(W + (size_t)(c0 + ct*16 + lr) * 512 + k0 + lg * 8);
            acc[ct] = __builtin_amdgcn_mfma_f32_16x16x32_bf16(af, bf, acc[ct], 0, 0, 0);
        }
    }
    if (z < 2) {
        ushort_t* out = (z == 0) ? q : k;
        #pragma unroll
        for (int ct = 0; ct < 4; ++ct) {
            int cg = c0 + ct*16 + lr;
            float bb = bias[cg];
            #pragma unroll
            for (int r2 = 0; r2 < 4; ++r2) {
                int row = r0 + lg*4 + r2;
                out[(size_t)row * 512 + cg] = f2bf((acc[ct][r2] + bb) * scale);
            }
        }
    } else {
        #pragma unroll
        for (int ct = 0; ct < 4; ++ct) {
            int cg = c0 + ct*16 + lr;
            float bb = bias[cg];
            int row = r0 + lg*4;
            int batch = row >> 12, j = row & 4095;
            ushort4 o;
            o.x = f2bf(acc[ct][0] + bb);
            o.y = f2bf(acc[ct][1] + bb);
            o.z = f2bf(acc[ct][2] + bb);
            o.w = f2bf(acc[ct][3] + bb);
            *(ushort4*)(v + (size_t)batch * (512*4096) + (size_t)cg * 4096 + j) = o;
        }
    }
}

// ---------------- flash attention, 32x32x16 MFMA.
// Block = 256 threads = 4 waves = 2 row-groups (32 q-rows each) x 2 channel-groups (256 c each).
// QK^T duplicated across the c-pair (no cross-wave reduce); PV/acc c-split -> 128 VGPR acc.
// K/V double-buffered in LDS via global_load_lds (linear dest + pre-swizzled source, rule 21),
// counted vmcnt(16) pipeline; swapped QK^T -> lane-local softmax; T12 repack; T13 defer-max.
__global__ __launch_bounds__(256, 1) void attn_kernel(const ushort_t* __restrict__ q, const ushort_t* __restrict__ k,
                          const ushort_t* __restrict__ vt, ushort_t* __restrict__ O) {
    __shared__ char slds[131072];   // 2 bufs x (K tile 32KB + V tile 32KB)
    const int tid  = threadIdx.x;
    const int w    = tid >> 6;
    const int lane = tid & 63;
    const int l31  = lane & 31;
    const int h    = lane >> 5;
    const int rg   = w >> 1;        // row-group: q-rows [i0, i0+32)
    const int cgr  = w & 1;         // channel-group: c in [cgr*256, cgr*256+256)
    const int batch = blockIdx.y;
    const int i0 = blockIdx.x * 64 + rg * 32;
    const char* kbase = (const char*)(k  + (size_t)batch * (4096 * 512));
    const char* vbase = (const char*)(vt + (size_t)batch * (512 * 4096));
    const ushort_t* qb = q + (size_t)batch * (4096 * 512);

    // Q fragments: lane holds Q[i0 + l31][16*kk + 8*h .. +8]  (B-operand of mfma(K,Q))
    s16x8 qf[32];
    {
        const ushort_t* qrow = qb + (size_t)(i0 + l31) * 512 + h * 8;
        #pragma unroll
        for (int kk = 0; kk < 32; ++kk) qf[kk] = *(const s16x8*)(qrow + kk * 16);
    }

    f32x16 acc[8];
    #pragma unroll
    for (int t = 0; t < 8; ++t) acc[t] = (f32x16){};
    float mrun = -1e30f, srun = 0.f;

    const int sp = w & 1;           // stage row parity within the K/V stager pair
    const int vq = lane >> 2;       // V staging: c-within-row index

    auto STAGE = [&](int buf, int j0s) {
        char* lb = slds + buf * 65536;
        if (w < 2) {
            // K tile rows 0..31 (1KB each): lds slot6=lane holds global granule lane^(p&7)
            const char* g = kbase + (size_t)j0s * 1024;
            #pragma unroll
            for (int r = 0; r < 16; ++r) {
                int p = r * 2 + sp;
                __builtin_amdgcn_global_load_lds(
                    (const __attribute__((address_space(1))) void*)(g + p * 1024 + ((lane ^ (p & 7)) << 4)),
                    (__attribute__((address_space(3))) void*)(lb + p * 1024), 16, 0, 0);
            }
        } else {
            // V^T tile: 64B per c-row; lds slot (lane&3) holds global slot (lane&3)^(c&3)
            const char* g = vbase + (size_t)j0s * 2;
            char* lv = lb + 32768;
            #pragma unroll
            for (int r = 0; r < 16; ++r) {
                int p = r * 2 + sp;
                int crow = p * 16 + vq;
                int scol = ((lane & 3) ^ (vq & 3)) << 4;
                __builtin_amdgcn_global_load_lds(
                    (const __attribute__((address_space(1))) void*)(g + (size_t)crow * 8192 + scol),
                    (__attribute__((address_space(3))) void*)(lv + p * 1024), 16, 0, 0);
            }
        }
    };

    STAGE(0, 0);

    for (int t = 0; t < 128; ++t) {
        const int cur = t & 1;
        if (t < 127) {
            STAGE(cur ^ 1, (t + 1) * 32);
            asm volatile("s_waitcnt vmcnt(16)" ::: "memory");
        } else {
            asm volatile("s_waitcnt vmcnt(0)" ::: "memory");
        }
        __builtin_amdgcn_s_barrier();
        asm volatile("" ::: "memory");

        const char* kl = slds + cur * 65536;
        const char* vl = kl + 32768;

        // S^T[j 32][i 32] = K_tile(A) . Q^T(B), two accumulation chains
        f32x16 sa = {}, sb = {};
        #pragma unroll
        for (int kk = 0; kk < 32; kk += 2) {
            s16x8 kf0 = *(const s16x8*)(kl + l31 * 1024 + ((((kk    ) << 1) + h) ^ (lane & 7)) * 16);
            s16x8 kf1 = *(const s16x8*)(kl + l31 * 1024 + ((((kk + 1) << 1) + h) ^ (lane & 7)) * 16);
            sa = __builtin_amdgcn_mfma_f32_32x32x16_bf16(kf0, qf[kk],     sa, 0, 0, 0);
            sb = __builtin_amdgcn_mfma_f32_32x32x16_bf16(kf1, qf[kk + 1], sb, 0, 0, 0);
        }
        f32x16 st = sa + sb;  // reg r: S^T[j = (r&3)+8*(r>>2)+4*h][i = i0+l31]

        // online softmax per q-column i (16 regs + partner half via xor-32)
        float tm = st[0];
        #pragma unroll
        for (int r = 1; r < 16; ++r) tm = fmaxf(tm, st[r]);
        tm = fmaxf(tm, __shfl_xor(tm, 32));
        if (!__all(tm <= mrun + 8.f)) {       // T13 defer-max, THR=8
            float mn = fmaxf(mrun, tm);
            float rs = __expf(mrun - mn);
            #pragma unroll
            for (int c = 0; c < 8; ++c) acc[c] *= rs;
            srun *= rs;
            mrun = mn;
        }
        f32x16 p;
        #pragma unroll
        for (int r = 0; r < 16; ++r) p[r] = __expf(st[r] - mrun);
        float ts = p[0];
        #pragma unroll
        for (int r = 1; r < 16; ++r) ts += p[r];
        srun += ts + __shfl_xor(ts, 32);

        // repack P^T -> PV B-fragments (T12 structure, shfl_xor32 exchange)
        unsigned u0 = pkbf(p[0],  p[1]),  v0 = pkbf(p[2],  p[3]);
        unsigned u1 = pkbf(p[4],  p[5]),  v1 = pkbf(p[6],  p[7]);
        unsigned u2 = pkbf(p[8],  p[9]),  v2 = pkbf(p[10], p[11]);
        unsigned u3 = pkbf(p[12], p[13]), v3 = pkbf(p[14], p[15]);
        unsigned xu0 = (unsigned)__shfl_xor((int)(h ? u0 : u1), 32);
        unsigned xv0 = (unsigned)__shfl_xor((int)(h ? v0 : v1), 32);
        unsigned xu1 = (unsigned)__shfl_xor((int)(h ? u2 : u3), 32);
        unsigned xv1 = (unsigned)__shfl_xor((int)(h ? v2 : v3), 32);
        union { unsigned u[4]; s16x8 v; } pf0u, pf1u;
        pf0u.u[0] = h ? xu0 : u0;  pf0u.u[1] = h ? xv0 : v0;
        pf0u.u[2] = h ? u1  : xu0; pf0u.u[3] = h ? v1  : xv0;
        pf1u.u[0] = h ? xu1 : u2;  pf1u.u[1] = h ? xv1 : v2;
        pf1u.u[2] = h ? u3  : xu1; pf1u.u[3] = h ? v3  : xv1;
        s16x8 pf0 = pf0u.v, pf1 = pf1u.v;

        // O^T[c][i] += V^T_tile(A) . P^T(B), c-split: this wave's 256 channels
        #pragma unroll
        for (int ct = 0; ct < 8; ++ct) {
            const char* vrow = vl + (cgr * 256 + ct * 32 + l31) * 64;
            s16x8 vf0 = *(const s16x8*)(vrow + ((( h    ) ^ (lane & 3)) << 4));
            s16x8 vf1 = *(const s16x8*)(vrow + (((2 | h) ^ (lane & 3)) << 4));
            acc[ct] = __builtin_amdgcn_mfma_f32_32x32x16_bf16(vf0, pf0, acc[ct], 0, 0, 0);
            acc[ct] = __builtin_amdgcn_mfma_f32_32x32x16_bf16(vf1, pf1, acc[ct], 0, 0, 0);
        }
        asm volatile("" ::: "memory");
        __builtin_amdgcn_s_barrier();
    }

    float inv = 1.f / srun;
    ushort_t* orow = O + (size_t)batch * (4096 * 512) + (size_t)(i0 + l31) * 512 + cgr * 256;
    #pragma unroll
    for (int ct = 0; ct < 8; ++ct) {
        #pragma unroll
        for (int g2 = 0; g2 < 4; ++g2) {
            ushort4 o;
            o.x = f2bf(acc[ct][g2 * 4 + 0] * inv);
            o.y = f2bf(acc[ct][g2 * 4 + 1] * inv);
            o.z = f2bf(acc[ct][g2 * 4 + 2] * inv);
            o.w = f2bf(acc[ct][g2 * 4 + 3] * inv);
            *(ushort4*)(orow + ct * 32 + g2 * 8 + h * 4) = o;
        }
    }
}

// ---------------- final projection + bias + residual (fp32 out)
__global__ __launch_bounds__(256) void proj_kernel(const ushort_t* __restrict__ O, const ushort_t* __restrict__ wt,
                          const float* __restrict__ bp, const float* __restrict__ x, float* __restrict__ out) {
    int wid = threadIdx.x >> 6, lane = threadIdx.x & 63;
    int lr = lane & 15, lg = lane >> 4;
    int r0 = blockIdx.x * 64 + wid * 16;
    int c0 = blockIdx.y * 64;
    const ushort_t* W = wt + (size_t)3 * 262144;
    const ushort_t* arow = O + (size_t)(r0 + lr) * 512 + lg * 8;
    f32x4 acc[4] = {};
    for (int k0 = 0; k0 < 512; k0 += 32) {
        s16x8 af = *(const s16x8*)(arow + k0);
        #pragma unroll
        for (int ct = 0; ct < 4; ++ct) {
            s16x8 bf = *(const s16x8*)(W + (size_t)(c0 + ct*16 + lr) * 512 + k0 + lg * 8);
            acc[ct] = __builtin_amdgcn_mfma_f32_16x16x32_bf16(af, bf, acc[ct], 0, 0, 0);
        }
    }
    #pragma unroll
    for (int ct = 0; ct < 4; ++ct) {
        int cg = c0 + ct*16 + lr;
        float bb = bp[cg];
        #pragma unroll
        for (int r2 = 0; r2 < 4; ++r2) {
            size_t idx = (size_t)(r0 + lg*4 + r2) * 512 + cg;
            out[idx] = acc[ct][r2] + bb + x[idx];
        }
    }
}

extern "C" void kernel_launch(void* const* d_in, const int* in_sizes, int n_in,
                              void* d_out, int out_size, void* d_ws, size_t ws_size,
                              hipStream_t stream) {
    (void)in_sizes; (void)n_in; (void)out_size; (void)ws_size;
    const float* x     = (const float*)d_in[0];
    const float* gamma = (const float*)d_in[1];
    const float* beta  = (const float*)d_in[2];
    const float* wq    = (const float*)d_in[3];
    const float* bq    = (const float*)d_in[4];
    const float* wk    = (const float*)d_in[5];
    const float* bk    = (const float*)d_in[6];
    const float* wv    = (const float*)d_in[7];
    const float* bv    = (const float*)d_in[8];
    const float* wp    = (const float*)d_in[9];
    const float* bp    = (const float*)d_in[10];
    float* out = (float*)d_out;

    char* ws = (char*)d_ws;
    ushort_t* wt   = (ushort_t*)(ws);                 // 2 MB  (4x 512x512 bf16, transposed)
    float*    stats= (float*)(ws + (2ull<<20));       // 1 KB
    ushort_t* xn   = (ushort_t*)(ws + (4ull<<20));    // 16 MB
    ushort_t* qb   = (ushort_t*)(ws + (20ull<<20));   // 16 MB (pre-scaled by C^-0.5)
    ushort_t* kb   = (ushort_t*)(ws + (36ull<<20));   // 16 MB
    ushort_t* vt   = (ushort_t*)(ws + (52ull<<20));   // 16 MB ([b][c][n] transposed)
    ushort_t* Ob   = (ushort_t*)(ws + (68ull<<20));   // 16 MB

    hipLaunchKernelGGL(wconv_kernel,    dim3(4096),       dim3(256), 0, stream, wq, wk, wv, wp, wt);
    hipLaunchKernelGGL(gn_stats_kernel, dim3(128),        dim3(256), 0, stream, x, stats);
    hipLaunchKernelGGL(gn_norm_kernel,  dim3(8192),       dim3(256), 0, stream, x, gamma, beta, stats, xn);
    hipLaunchKernelGGL(qkv_kernel,      dim3(256, 8, 3),  dim3(256), 0, stream, xn, wt, bq, bk, bv, qb, kb, vt);
    hipLaunchKernelGGL(attn_kernel,     dim3(64, 4),      dim3(256), 0, stream, qb, kb, vt, Ob);
    hipLaunchKernelGGL(proj_kernel,     dim3(256, 8),     dim3(256), 0, stream, Ob, wt, bp, x, out);
}

// Round 4
// 636.839 us; speedup vs baseline: 4.0959x; 1.7194x over previous
//
#include <hip/hip_runtime.h>
#include <hip/hip_bf16.h>

typedef __attribute__((ext_vector_type(4))) float f32x4;
typedef __attribute__((ext_vector_type(8))) short s16x8;
typedef unsigned short ushort_t;

// Sizes: B=4, H=W=64 -> N=4096, C=512, GROUPS=32 (cg=16)
#define N_DIM 4096
#define C_DIM 512

static __device__ __forceinline__ unsigned short f2bf(float f) {
    union { float f; unsigned u; } v; v.f = f;
    unsigned r = v.u + 0x7FFFu + ((v.u >> 16) & 1u);
    return (unsigned short)(r >> 16);
}

// ---------------- GroupNorm stats: one block per (b,g), reduce 4096*16 elems
__global__ void gn_stats_kernel(const float* __restrict__ x, float* __restrict__ stats) {
    int bg = blockIdx.x;
    int b = bg >> 5, g = bg & 31;
    const float* base = x + (size_t)b * (N_DIM * C_DIM) + g * 16;
    float sum = 0.f, ss = 0.f;
    for (int n = threadIdx.x; n < N_DIM; n += 256) {
        const float4* p = (const float4*)(base + (size_t)n * C_DIM);
        #pragma unroll
        for (int t = 0; t < 4; ++t) {
            float4 v = p[t];
            sum += v.x + v.y + v.z + v.w;
            ss  += v.x*v.x + v.y*v.y + v.z*v.z + v.w*v.w;
        }
    }
    #pragma unroll
    for (int o = 32; o > 0; o >>= 1) {
        sum += __shfl_down(sum, o);
        ss  += __shfl_down(ss, o);
    }
    __shared__ float red[8];
    int wid = threadIdx.x >> 6, lane = threadIdx.x & 63;
    if (lane == 0) { red[wid*2] = sum; red[wid*2+1] = ss; }
    __syncthreads();
    if (threadIdx.x == 0) {
        sum = red[0]+red[2]+red[4]+red[6];
        ss  = red[1]+red[3]+red[5]+red[7];
        float mean = sum * (1.f/65536.f);
        float var  = ss  * (1.f/65536.f) - mean*mean;
        stats[bg*2]   = mean;
        stats[bg*2+1] = rsqrtf(var + 1e-5f);
    }
}

// ---------------- normalize + gamma/beta + cast to bf16
__global__ void gn_norm_kernel(const float* __restrict__ x, const float* __restrict__ gamma,
                               const float* __restrict__ beta, const float* __restrict__ stats,
                               ushort_t* __restrict__ xn) {
    size_t i = ((size_t)blockIdx.x * 256 + threadIdx.x) * 4;
    int c = (int)(i & 511);
    int b = (int)(i >> 21);
    int bg = b*32 + (c >> 4);
    float mean = stats[bg*2], rstd = stats[bg*2+1];
    float4 v  = *(const float4*)(x + i);
    float4 ga = *(const float4*)(gamma + c);
    float4 be = *(const float4*)(beta + c);
    ushort4 o;
    o.x = f2bf((v.x - mean) * rstd * ga.x + be.x);
    o.y = f2bf((v.y - mean) * rstd * ga.y + be.y);
    o.z = f2bf((v.z - mean) * rstd * ga.z + be.z);
    o.w = f2bf((v.w - mean) * rstd * ga.w + be.w);
    *(ushort4*)(xn + i) = o;
}

// ---------------- weights: fp32 [Cin][Cout] -> bf16 transposed [Cout][Cin], 4 mats
__global__ void wconv_kernel(const float* __restrict__ wq, const float* __restrict__ wk,
                             const float* __restrict__ wv, const float* __restrict__ wp,
                             ushort_t* __restrict__ wt) {
    int idx = blockIdx.x * 256 + threadIdx.x;
    int m = idx >> 18;
    int r = idx & 262143;
    int ci = r >> 9, co = r & 511;
    const float* w = (m == 0) ? wq : (m == 1) ? wk : (m == 2) ? wv : wp;
    wt[(size_t)m * 262144 + (size_t)co * 512 + ci] = f2bf(w[(size_t)ci * 512 + co]);
}

// ---------------- QKV GEMM: xn[16384,512] @ Wt -> q,k (row-major, q pre-scaled), v (transposed per batch)
__global__ __launch_bounds__(256) void qkv_kernel(const ushort_t* __restrict__ xn, const ushort_t* __restrict__ wt,
                         const float* __restrict__ bq, const float* __restrict__ bk, const float* __restrict__ bv,
                         ushort_t* __restrict__ q, ushort_t* __restrict__ k, ushort_t* __restrict__ v) {
    int z = blockIdx.z;
    const ushort_t* W = wt + (size_t)z * 262144;
    const float* bias = (z == 0) ? bq : (z == 1) ? bk : bv;
    float scale = (z == 0) ? 0.04419417382415922f : 1.0f;  // 512^-0.5 folded into q
    int wid = threadIdx.x >> 6, lane = threadIdx.x & 63;
    int lr = lane & 15, lg = lane >> 4;
    int r0 = blockIdx.x * 64 + wid * 16;
    int c0 = blockIdx.y * 64;
    const ushort_t* arow = xn + (size_t)(r0 + lr) * 512 + lg * 8;
    f32x4 acc[4] = {};
    for (int k0 = 0; k0 < 512; k0 += 32) {
        s16x8 af = *(const s16x8*)(arow + k0);
        #pragma unroll
        for (int ct = 0; ct < 4; ++ct) {
            s16x8 bf = *(const s16x8*)(W + (size_t)(c0 + ct*16 + lr) * 512 + k0 + lg * 8);
            acc[ct] = __builtin_amdgcn_mfma_f32_16x16x32_bf16(af, bf, acc[ct], 0, 0, 0);
        }
    }
    if (z < 2) {
        ushort_t* out = (z == 0) ? q : k;
        #pragma unroll
        for (int ct = 0; ct < 4; ++ct) {
            int cg = c0 + ct*16 + lr;
            float bb = bias[cg];
            #pragma unroll
            for (int r2 = 0; r2 < 4; ++r2) {
                int row = r0 + lg*4 + r2;
                out[(size_t)row * 512 + cg] = f2bf((acc[ct][r2] + bb) * scale);
            }
        }
    } else {
        #pragma unroll
        for (int ct = 0; ct < 4; ++ct) {
            int cg = c0 + ct*16 + lr;
            float bb = bias[cg];
            int row = r0 + lg*4;
            int batch = row >> 12, j = row & 4095;
            ushort4 o;
            o.x = f2bf(acc[ct][0] + bb);
            o.y = f2bf(acc[ct][1] + bb);
            o.z = f2bf(acc[ct][2] + bb);
            o.w = f2bf(acc[ct][3] + bb);
            *(ushort4*)(v + (size_t)batch * (512*4096) + (size_t)cg * 4096 + j) = o;
        }
    }
}

// ---------------- flash attention (R1 proven 16x16 compute, spill-free 212-VGPR class)
// + R3-verified staging: double-buffered global_load_lds (linear LDS dest, pre-swizzled
// global source, rule 21) with counted vmcnt(16) so next-tile loads fly across barriers.
__global__ __launch_bounds__(256, 1) void attn_kernel(const ushort_t* __restrict__ q, const ushort_t* __restrict__ k,
                          const ushort_t* __restrict__ vt, ushort_t* __restrict__ O) {
    __shared__ char slds[131072];   // 2 bufs x (K tile 32KB + V tile 32KB)
    const int tid = threadIdx.x;
    const int w = tid >> 6, lane = tid & 63;
    const int lr = lane & 15, lg = lane >> 4;
    const int batch = blockIdx.y;
    const int i0 = blockIdx.x * 64 + w * 16;
    const char* kb = (const char*)(k  + (size_t)batch * (4096 * 512));
    const char* vb = (const char*)(vt + (size_t)batch * (512 * 4096));
    const ushort_t* qb = q + (size_t)batch * (4096 * 512);

    // Q fragments (B-operand of mfma(K,Q)): lane holds q[(i0+lr)][t*32 + lg*8 .. +8]
    s16x8 qf[16];
    {
        const ushort_t* qrow = qb + (size_t)(i0 + lr) * 512 + lg * 8;
        #pragma unroll
        for (int t = 0; t < 16; ++t) qf[t] = *(const s16x8*)(qrow + t * 32);
    }

    f32x4 oacc[32];
    #pragma unroll
    for (int t = 0; t < 32; ++t) oacc[t] = (f32x4){0.f,0.f,0.f,0.f};
    float m = -1e30f, s = 0.f;

    // V staging lane constant: granule (lane&3) of c-row (lane>>2) holds global granule (lane&3)^((c>>1)&3)
    const int vswz = ((lane & 3) ^ ((lane >> 3) & 3)) << 4;

    auto STAGE = [&](int buf, int j0) {
        char* lb = slds + buf * 65536;
        const char* gk = kb + (size_t)j0 * 1024;
        #pragma unroll
        for (int r = 0; r < 8; ++r) {
            int row = w * 8 + r;             // row&7 == r
            __builtin_amdgcn_global_load_lds(
                (const __attribute__((address_space(1))) void*)(gk + (size_t)row * 1024 + ((lane ^ r) << 4)),
                (__attribute__((address_space(3))) void*)(lb + row * 1024), 16, 0, 0);
        }
        const char* gv = vb + (size_t)j0 * 2;
        char* lv = lb + 32768;
        #pragma unroll
        for (int r = 0; r < 8; ++r) {
            int p = w * 8 + r;
            int c = p * 16 + (lane >> 2);
            __builtin_amdgcn_global_load_lds(
                (const __attribute__((address_space(1))) void*)(gv + (size_t)c * 8192 + vswz),
                (__attribute__((address_space(3))) void*)(lv + p * 1024), 16, 0, 0);
        }
    };

    STAGE(0, 0);

    for (int t = 0; t < 128; ++t) {
        const int cur = t & 1;
        if (t < 127) {
            STAGE(cur ^ 1, (t + 1) * 32);
            asm volatile("s_waitcnt vmcnt(16)" ::: "memory");
        } else {
            asm volatile("s_waitcnt vmcnt(0)" ::: "memory");
        }
        __builtin_amdgcn_s_barrier();
        asm volatile("" ::: "memory");

        const char* kl = slds + cur * 65536;
        const char* vl = kl + 32768;

        // S^T = K_tile . Q^T : two 16x16 j-tiles, 2 chains each for ILP
        f32x4 sa = {0,0,0,0}, sb = {0,0,0,0}, sc2 = {0,0,0,0}, sd = {0,0,0,0};
        #pragma unroll
        for (int tt = 0; tt < 16; tt += 2) {
            s16x8 k0f = *(const s16x8*)(kl + lr * 1024        + ((tt*64 + lg*16)     ^ ((lr&7)*16)));
            s16x8 k1f = *(const s16x8*)(kl + lr * 1024        + (((tt+1)*64 + lg*16) ^ ((lr&7)*16)));
            s16x8 k2f = *(const s16x8*)(kl + (16+lr) * 1024   + ((tt*64 + lg*16)     ^ ((lr&7)*16)));
            s16x8 k3f = *(const s16x8*)(kl + (16+lr) * 1024   + (((tt+1)*64 + lg*16) ^ ((lr&7)*16)));
            sa  = __builtin_amdgcn_mfma_f32_16x16x32_bf16(k0f, qf[tt],   sa,  0,0,0);
            sb  = __builtin_amdgcn_mfma_f32_16x16x32_bf16(k1f, qf[tt+1], sb,  0,0,0);
            sc2 = __builtin_amdgcn_mfma_f32_16x16x32_bf16(k2f, qf[tt],   sc2, 0,0,0);
            sd  = __builtin_amdgcn_mfma_f32_16x16x32_bf16(k3f, qf[tt+1], sd,  0,0,0);
        }
        f32x4 s1 = sa + sb;   // S^T[j0+4*lg+r][i0+lr]
        f32x4 s2 = sc2 + sd;  // S^T[j0+16+4*lg+r][i0+lr]

        // online softmax (per q-row i = lr column; reduce over lanes lg=0..3)
        float tm = fmaxf(fmaxf(fmaxf(s1[0], s1[1]), fmaxf(s1[2], s1[3])),
                         fmaxf(fmaxf(s2[0], s2[1]), fmaxf(s2[2], s2[3])));
        tm = fmaxf(tm, __shfl_xor(tm, 16));
        tm = fmaxf(tm, __shfl_xor(tm, 32));
        if (__any(tm > m)) {
            float mnew = fmaxf(m, tm);
            float resc = __expf(m - mnew);
            #pragma unroll
            for (int t2 = 0; t2 < 32; ++t2) oacc[t2] *= resc;
            s *= resc;
            m = mnew;
        }
        f32x4 p1, p2;
        #pragma unroll
        for (int r2 = 0; r2 < 4; ++r2) { p1[r2] = __expf(s1[r2] - m); p2[r2] = __expf(s2[r2] - m); }
        float ts = p1[0]+p1[1]+p1[2]+p1[3] + p2[0]+p2[1]+p2[2]+p2[3];
        ts += __shfl_xor(ts, 16);
        ts += __shfl_xor(ts, 32);
        s += ts;

        // pack P to bf16 pairs; cross-lane gather into K=32 B-fragment layout
        unsigned w0 = (unsigned)f2bf(p1[0]) | ((unsigned)f2bf(p1[1]) << 16);
        unsigned w1 = (unsigned)f2bf(p1[2]) | ((unsigned)f2bf(p1[3]) << 16);
        unsigned w2 = (unsigned)f2bf(p2[0]) | ((unsigned)f2bf(p2[1]) << 16);
        unsigned w3 = (unsigned)f2bf(p2[2]) | ((unsigned)f2bf(p2[3]) << 16);
        int s0l = lr + ((lg & 1) << 5);
        int s1l = s0l + 16;
        unsigned a0 = (unsigned)__shfl((int)w0, s0l), a1 = (unsigned)__shfl((int)w1, s0l);
        unsigned b0 = (unsigned)__shfl((int)w0, s1l), b1 = (unsigned)__shfl((int)w1, s1l);
        unsigned c0w = (unsigned)__shfl((int)w2, s0l), c1 = (unsigned)__shfl((int)w3, s0l);
        unsigned d0 = (unsigned)__shfl((int)w2, s1l), d1 = (unsigned)__shfl((int)w3, s1l);
        bool hi = (lg >= 2);
        union { unsigned u[4]; s16x8 v8; } pu;
        pu.u[0] = hi ? c0w : a0;
        pu.u[1] = hi ? c1  : a1;
        pu.u[2] = hi ? d0  : b0;
        pu.u[3] = hi ? d1  : b1;
        s16x8 pf = pu.v8;

        // O^T += V^T_tile . P^T
        #pragma unroll
        for (int ct = 0; ct < 32; ++ct) {
            int c = ct * 16 + lr;
            s16x8 vf = *(const s16x8*)(vl + c * 64 + ((lg ^ ((lr >> 1) & 3)) << 4));
            oacc[ct] = __builtin_amdgcn_mfma_f32_16x16x32_bf16(vf, pf, oacc[ct], 0,0,0);
        }
        asm volatile("" ::: "memory");
        __builtin_amdgcn_s_barrier();
    }
    float inv = 1.f / s;
    ushort_t* orow = O + (size_t)batch * (4096*512) + (size_t)(i0 + lr) * 512 + lg * 4;
    #pragma unroll
    for (int ct = 0; ct < 32; ++ct) {
        ushort4 o;
        o.x = f2bf(oacc[ct][0] * inv);
        o.y = f2bf(oacc[ct][1] * inv);
        o.z = f2bf(oacc[ct][2] * inv);
        o.w = f2bf(oacc[ct][3] * inv);
        *(ushort4*)(orow + ct * 16) = o;
    }
}

// ---------------- final projection + bias + residual (fp32 out)
__global__ __launch_bounds__(256) void proj_kernel(const ushort_t* __restrict__ O, const ushort_t* __restrict__ wt,
                          const float* __restrict__ bp, const float* __restrict__ x, float* __restrict__ out) {
    int wid = threadIdx.x >> 6, lane = threadIdx.x & 63;
    int lr = lane & 15, lg = lane >> 4;
    int r0 = blockIdx.x * 64 + wid * 16;
    int c0 = blockIdx.y * 64;
    const ushort_t* W = wt + (size_t)3 * 262144;
    const ushort_t* arow = O + (size_t)(r0 + lr) * 512 + lg * 8;
    f32x4 acc[4] = {};
    for (int k0 = 0; k0 < 512; k0 += 32) {
        s16x8 af = *(const s16x8*)(arow + k0);
        #pragma unroll
        for (int ct = 0; ct < 4; ++ct) {
            s16x8 bf = *(const s16x8*)(W + (size_t)(c0 + ct*16 + lr) * 512 + k0 + lg * 8);
            acc[ct] = __builtin_amdgcn_mfma_f32_16x16x32_bf16(af, bf, acc[ct], 0, 0, 0);
        }
    }
    #pragma unroll
    for (int ct = 0; ct < 4; ++ct) {
        int cg = c0 + ct*16 + lr;
        float bb = bp[cg];
        #pragma unroll
        for (int r2 = 0; r2 < 4; ++r2) {
            size_t idx = (size_t)(r0 + lg*4 + r2) * 512 + cg;
            out[idx] = acc[ct][r2] + bb + x[idx];
        }
    }
}

extern "C" void kernel_launch(void* const* d_in, const int* in_sizes, int n_in,
                              void* d_out, int out_size, void* d_ws, size_t ws_size,
                              hipStream_t stream) {
    (void)in_sizes; (void)n_in; (void)out_size; (void)ws_size;
    const float* x     = (const float*)d_in[0];
    const float* gamma = (const float*)d_in[1];
    const float* beta  = (const float*)d_in[2];
    const float* wq    = (const float*)d_in[3];
    const float* bq    = (const float*)d_in[4];
    const float* wk    = (const float*)d_in[5];
    const float* bk    = (const float*)d_in[6];
    const float* wv    = (const float*)d_in[7];
    const float* bv    = (const float*)d_in[8];
    const float* wp    = (const float*)d_in[9];
    const float* bp    = (const float*)d_in[10];
    float* out = (float*)d_out;

    char* ws = (char*)d_ws;
    ushort_t* wt   = (ushort_t*)(ws);                 // 2 MB  (4x 512x512 bf16, transposed)
    float*    stats= (float*)(ws + (2ull<<20));       // 1 KB
    ushort_t* xn   = (ushort_t*)(ws + (4ull<<20));    // 16 MB
    ushort_t* qb   = (ushort_t*)(ws + (20ull<<20));   // 16 MB (pre-scaled by C^-0.5)
    ushort_t* kb   = (ushort_t*)(ws + (36ull<<20));   // 16 MB
    ushort_t* vt   = (ushort_t*)(ws + (52ull<<20));   // 16 MB ([b][c][n] transposed)
    ushort_t* Ob   = (ushort_t*)(ws + (68ull<<20));   // 16 MB

    hipLaunchKernelGGL(wconv_kernel,    dim3(4096),       dim3(256), 0, stream, wq, wk, wv, wp, wt);
    hipLaunchKernelGGL(gn_stats_kernel, dim3(128),        dim3(256), 0, stream, x, stats);
    hipLaunchKernelGGL(gn_norm_kernel,  dim3(8192),       dim3(256), 0, stream, x, gamma, beta, stats, xn);
    hipLaunchKernelGGL(qkv_kernel,      dim3(256, 8, 3),  dim3(256), 0, stream, xn, wt, bq, bk, bv, qb, kb, vt);
    hipLaunchKernelGGL(attn_kernel,     dim3(64, 4),      dim3(256), 0, stream, qb, kb, vt, Ob);
    hipLaunchKernelGGL(proj_kernel,     dim3(256, 8),     dim3(256), 0, stream, Ob, wt, bp, x, out);
}

// Round 5
// 632.152 us; speedup vs baseline: 4.1262x; 1.0074x over previous
//
#include <hip/hip_runtime.h>
#include <hip/hip_bf16.h>

typedef __attribute__((ext_vector_type(4))) float f32x4;
typedef __attribute__((ext_vector_type(8))) short s16x8;
typedef unsigned short ushort_t;

// Sizes: B=4, H=W=64 -> N=4096, C=512, GROUPS=32 (cg=16)
#define N_DIM 4096
#define C_DIM 512

static __device__ __forceinline__ unsigned short f2bf(float f) {
    union { float f; unsigned u; } v; v.f = f;
    unsigned r = v.u + 0x7FFFu + ((v.u >> 16) & 1u);
    return (unsigned short)(r >> 16);
}

// ---------------- GroupNorm stats: one block per (b,g), reduce 4096*16 elems
__global__ void gn_stats_kernel(const float* __restrict__ x, float* __restrict__ stats) {
    int bg = blockIdx.x;
    int b = bg >> 5, g = bg & 31;
    const float* base = x + (size_t)b * (N_DIM * C_DIM) + g * 16;
    float sum = 0.f, ss = 0.f;
    for (int n = threadIdx.x; n < N_DIM; n += 256) {
        const float4* p = (const float4*)(base + (size_t)n * C_DIM);
        #pragma unroll
        for (int t = 0; t < 4; ++t) {
            float4 v = p[t];
            sum += v.x + v.y + v.z + v.w;
            ss  += v.x*v.x + v.y*v.y + v.z*v.z + v.w*v.w;
        }
    }
    #pragma unroll
    for (int o = 32; o > 0; o >>= 1) {
        sum += __shfl_down(sum, o);
        ss  += __shfl_down(ss, o);
    }
    __shared__ float red[8];
    int wid = threadIdx.x >> 6, lane = threadIdx.x & 63;
    if (lane == 0) { red[wid*2] = sum; red[wid*2+1] = ss; }
    __syncthreads();
    if (threadIdx.x == 0) {
        sum = red[0]+red[2]+red[4]+red[6];
        ss  = red[1]+red[3]+red[5]+red[7];
        float mean = sum * (1.f/65536.f);
        float var  = ss  * (1.f/65536.f) - mean*mean;
        stats[bg*2]   = mean;
        stats[bg*2+1] = rsqrtf(var + 1e-5f);
    }
}

// ---------------- normalize + gamma/beta + cast to bf16
__global__ void gn_norm_kernel(const float* __restrict__ x, const float* __restrict__ gamma,
                               const float* __restrict__ beta, const float* __restrict__ stats,
                               ushort_t* __restrict__ xn) {
    size_t i = ((size_t)blockIdx.x * 256 + threadIdx.x) * 4;
    int c = (int)(i & 511);
    int b = (int)(i >> 21);
    int bg = b*32 + (c >> 4);
    float mean = stats[bg*2], rstd = stats[bg*2+1];
    float4 v  = *(const float4*)(x + i);
    float4 ga = *(const float4*)(gamma + c);
    float4 be = *(const float4*)(beta + c);
    ushort4 o;
    o.x = f2bf((v.x - mean) * rstd * ga.x + be.x);
    o.y = f2bf((v.y - mean) * rstd * ga.y + be.y);
    o.z = f2bf((v.z - mean) * rstd * ga.z + be.z);
    o.w = f2bf((v.w - mean) * rstd * ga.w + be.w);
    *(ushort4*)(xn + i) = o;
}

// ---------------- weights: fp32 [Cin][Cout] -> bf16 transposed [Cout][Cin], 4 mats
__global__ void wconv_kernel(const float* __restrict__ wq, const float* __restrict__ wk,
                             const float* __restrict__ wv, const float* __restrict__ wp,
                             ushort_t* __restrict__ wt) {
    int idx = blockIdx.x * 256 + threadIdx.x;
    int m = idx >> 18;
    int r = idx & 262143;
    int ci = r >> 9, co = r & 511;
    const float* w = (m == 0) ? wq : (m == 1) ? wk : (m == 2) ? wv : wp;
    wt[(size_t)m * 262144 + (size_t)co * 512 + ci] = f2bf(w[(size_t)ci * 512 + co]);
}

// ---------------- QKV GEMM: xn[16384,512] @ Wt -> q,k (row-major, q pre-scaled), v (transposed per batch)
__global__ __launch_bounds__(256) void qkv_kernel(const ushort_t* __restrict__ xn, const ushort_t* __restrict__ wt,
                         const float* __restrict__ bq, const float* __restrict__ bk, const float* __restrict__ bv,
                         ushort_t* __restrict__ q, ushort_t* __restrict__ k, ushort_t* __restrict__ v) {
    int z = blockIdx.z;
    const ushort_t* W = wt + (size_t)z * 262144;
    const float* bias = (z == 0) ? bq : (z == 1) ? bk : bv;
    float scale = (z == 0) ? 0.04419417382415922f : 1.0f;  // 512^-0.5 folded into q
    int wid = threadIdx.x >> 6, lane = threadIdx.x & 63;
    int lr = lane & 15, lg = lane >> 4;
    int r0 = blockIdx.x * 64 + wid * 16;
    int c0 = blockIdx.y * 64;
    const ushort_t* arow = xn + (size_t)(r0 + lr) * 512 + lg * 8;
    f32x4 acc[4] = {};
    for (int k0 = 0; k0 < 512; k0 += 32) {
        s16x8 af = *(const s16x8*)(arow + k0);
        #pragma unroll
        for (int ct = 0; ct < 4; ++ct) {
            s16x8 bf = *(const s16x8*)(W + (size_t)(c0 + ct*16 + lr) * 512 + k0 + lg * 8);
            acc[ct] = __builtin_amdgcn_mfma_f32_16x16x32_bf16(af, bf, acc[ct], 0, 0, 0);
        }
    }
    if (z < 2) {
        ushort_t* out = (z == 0) ? q : k;
        #pragma unroll
        for (int ct = 0; ct < 4; ++ct) {
            int cg = c0 + ct*16 + lr;
            float bb = bias[cg];
            #pragma unroll
            for (int r2 = 0; r2 < 4; ++r2) {
                int row = r0 + lg*4 + r2;
                out[(size_t)row * 512 + cg] = f2bf((acc[ct][r2] + bb) * scale);
            }
        }
    } else {
        #pragma unroll
        for (int ct = 0; ct < 4; ++ct) {
            int cg = c0 + ct*16 + lr;
            float bb = bias[cg];
            int row = r0 + lg*4;
            int batch = row >> 12, j = row & 4095;
            ushort4 o;
            o.x = f2bf(acc[ct][0] + bb);
            o.y = f2bf(acc[ct][1] + bb);
            o.z = f2bf(acc[ct][2] + bb);
            o.w = f2bf(acc[ct][3] + bb);
            *(ushort4*)(v + (size_t)batch * (512*4096) + (size_t)cg * 4096 + j) = o;
        }
    }
}

// ---------------- flash attention with c-split PV:
// QK^T + softmax per wave (16 q-rows each, as R4-verified); P^T + rescale factors go
// through LDS; PV is channel-split (each wave: 128 c x all 64 rows) so V-frags are read
// once per block (not 4x) and the P repack shuffles vanish. 3 barriers/iter; the P
// barrier drains lgkmcnt only (staging vmcnt pipeline preserved).
__global__ __launch_bounds__(256, 1) void attn_kernel(const ushort_t* __restrict__ q, const ushort_t* __restrict__ k,
                          const ushort_t* __restrict__ vt, ushort_t* __restrict__ O) {
    __shared__ char slds[131072 + 4096 + 256];  // stage bufs | plds | rlds
    char* plds = slds + 131072;
    float* rlds = (float*)(slds + 131072 + 4096);
    const int tid = threadIdx.x;
    const int w = tid >> 6, lane = tid & 63;
    const int lr = lane & 15, lg = lane >> 4;
    const int batch = blockIdx.y;
    const int i0 = blockIdx.x * 64;
    const char* kb = (const char*)(k  + (size_t)batch * (4096 * 512));
    const char* vb = (const char*)(vt + (size_t)batch * (512 * 4096));
    const ushort_t* qb = q + (size_t)batch * (4096 * 512);

    // Q fragments for this wave's 16 q-rows (B-operand of mfma(K,Q))
    s16x8 qf[16];
    {
        const ushort_t* qrow = qb + (size_t)(i0 + w * 16 + lr) * 512 + lg * 8;
        #pragma unroll
        for (int t = 0; t < 16; ++t) qf[t] = *(const s16x8*)(qrow + t * 32);
    }

    f32x4 acc[8][4];   // [c-tile within quarter][q-group]
    #pragma unroll
    for (int a = 0; a < 8; ++a)
        #pragma unroll
        for (int b = 0; b < 4; ++b) acc[a][b] = (f32x4){0.f,0.f,0.f,0.f};
    float m = -1e30f, s = 0.f;

    const int vswz = ((lane & 3) ^ ((lane >> 3) & 3)) << 4;

    auto STAGE = [&](int buf, int j0) {
        char* lb = slds + buf * 65536;
        const char* gk = kb + (size_t)j0 * 1024;
        #pragma unroll
        for (int r = 0; r < 8; ++r) {
            int row = w * 8 + r;             // row&7 == r
            __builtin_amdgcn_global_load_lds(
                (const __attribute__((address_space(1))) void*)(gk + (size_t)row * 1024 + ((lane ^ r) << 4)),
                (__attribute__((address_space(3))) void*)(lb + row * 1024), 16, 0, 0);
        }
        const char* gv = vb + (size_t)j0 * 2;
        char* lv = lb + 32768;
        #pragma unroll
        for (int r = 0; r < 8; ++r) {
            int p = w * 8 + r;
            int c = p * 16 + (lane >> 2);
            __builtin_amdgcn_global_load_lds(
                (const __attribute__((address_space(1))) void*)(gv + (size_t)c * 8192 + vswz),
                (__attribute__((address_space(3))) void*)(lv + p * 1024), 16, 0, 0);
        }
    };

    STAGE(0, 0);

    for (int t = 0; t < 128; ++t) {
        const int cur = t & 1;
        if (t < 127) {
            STAGE(cur ^ 1, (t + 1) * 32);
            asm volatile("s_waitcnt vmcnt(16)" ::: "memory");
        } else {
            asm volatile("s_waitcnt vmcnt(0)" ::: "memory");
        }
        __builtin_amdgcn_s_barrier();          // barrier A: tile cur ready, P free
        asm volatile("" ::: "memory");

        const char* kl = slds + cur * 65536;
        const char* vl = kl + 32768;

        // S^T = K_tile . Q^T : two 16x16 j-tiles, 2 chains each for ILP
        f32x4 sa = {0,0,0,0}, sb = {0,0,0,0}, sc2 = {0,0,0,0}, sd = {0,0,0,0};
        #pragma unroll
        for (int tt = 0; tt < 16; tt += 2) {
            s16x8 k0f = *(const s16x8*)(kl + lr * 1024        + ((tt*64 + lg*16)     ^ ((lr&7)*16)));
            s16x8 k1f = *(const s16x8*)(kl + lr * 1024        + (((tt+1)*64 + lg*16) ^ ((lr&7)*16)));
            s16x8 k2f = *(const s16x8*)(kl + (16+lr) * 1024   + ((tt*64 + lg*16)     ^ ((lr&7)*16)));
            s16x8 k3f = *(const s16x8*)(kl + (16+lr) * 1024   + (((tt+1)*64 + lg*16) ^ ((lr&7)*16)));
            sa  = __builtin_amdgcn_mfma_f32_16x16x32_bf16(k0f, qf[tt],   sa,  0,0,0);
            sb  = __builtin_amdgcn_mfma_f32_16x16x32_bf16(k1f, qf[tt+1], sb,  0,0,0);
            sc2 = __builtin_amdgcn_mfma_f32_16x16x32_bf16(k2f, qf[tt],   sc2, 0,0,0);
            sd  = __builtin_amdgcn_mfma_f32_16x16x32_bf16(k3f, qf[tt+1], sd,  0,0,0);
        }
        f32x4 s1 = sa + sb;   // S^T[4*lg+r][i0+16w+lr]
        f32x4 s2 = sc2 + sd;  // S^T[16+4*lg+r][i0+16w+lr]

        // online softmax (per q-row; reduce over lg via xor 16/32)
        float tm = fmaxf(fmaxf(fmaxf(s1[0], s1[1]), fmaxf(s1[2], s1[3])),
                         fmaxf(fmaxf(s2[0], s2[1]), fmaxf(s2[2], s2[3])));
        tm = fmaxf(tm, __shfl_xor(tm, 16));
        tm = fmaxf(tm, __shfl_xor(tm, 32));
        float resc = 1.f;
        if (__any(tm > m)) {
            float mnew = fmaxf(m, tm);
            resc = __expf(m - mnew);
            s *= resc;
            m = mnew;
        }
        f32x4 p1, p2;
        #pragma unroll
        for (int r2 = 0; r2 < 4; ++r2) { p1[r2] = __expf(s1[r2] - m); p2[r2] = __expf(s2[r2] - m); }
        float ts = p1[0]+p1[1]+p1[2]+p1[3] + p2[0]+p2[1]+p2[2]+p2[3];
        ts += __shfl_xor(ts, 16);
        ts += __shfl_xor(ts, 32);
        s += ts;

        // write P^T for this wave's q-group (g = w) into plds, B-frag layout with
        // 16B-granule XOR by (i&3); write rescale factor for owned rows.
        {
            unsigned w0 = (unsigned)f2bf(p1[0]) | ((unsigned)f2bf(p1[1]) << 16);
            unsigned w1 = (unsigned)f2bf(p1[2]) | ((unsigned)f2bf(p1[3]) << 16);
            unsigned w2 = (unsigned)f2bf(p2[0]) | ((unsigned)f2bf(p2[1]) << 16);
            unsigned w3 = (unsigned)f2bf(p2[2]) | ((unsigned)f2bf(p2[3]) << 16);
            char* prow = plds + w * 1024 + lr * 64 + ((lg & 1) << 3);
            *(uint2*)(prow + ((((lg >> 1)    ) ^ (lr & 3)) << 4)) = (uint2){w0, w1};
            *(uint2*)(prow + (((2 | (lg >> 1)) ^ (lr & 3)) << 4)) = (uint2){w2, w3};
            if (lg == 0) rlds[w * 16 + lr] = resc;
        }
        asm volatile("s_waitcnt lgkmcnt(0)" ::: "memory");
        __builtin_amdgcn_s_barrier();          // barrier B: P + resc visible
        asm volatile("" ::: "memory");

        // rescale this wave's O slice (per q-row factors from owner waves)
        {
            float rf0 = rlds[lr], rf1 = rlds[16 + lr], rf2 = rlds[32 + lr], rf3 = rlds[48 + lr];
            if (__any(rf0 != 1.f || rf1 != 1.f || rf2 != 1.f || rf3 != 1.f)) {
                #pragma unroll
                for (int ct = 0; ct < 8; ++ct) {
                    acc[ct][0] *= rf0; acc[ct][1] *= rf1; acc[ct][2] *= rf2; acc[ct][3] *= rf3;
                }
            }
        }
        // read the 4 P fragments (one per q-group)
        s16x8 pf[4];
        #pragma unroll
        for (int g = 0; g < 4; ++g)
            pf[g] = *(const s16x8*)(plds + g * 1024 + lr * 64 + ((lg ^ (lr & 3)) << 4));

        // PV: this wave's 128-channel quarter x all 4 q-groups
        #pragma unroll
        for (int ct = 0; ct < 8; ++ct) {
            int c = w * 128 + ct * 16 + lr;
            s16x8 vf = *(const s16x8*)(vl + c * 64 + ((lg ^ ((lr >> 1) & 3)) << 4));
            #pragma unroll
            for (int g = 0; g < 4; ++g)
                acc[ct][g] = __builtin_amdgcn_mfma_f32_16x16x32_bf16(vf, pf[g], acc[ct][g], 0,0,0);
        }
        asm volatile("" ::: "memory");
        __builtin_amdgcn_s_barrier();          // barrier C: PV done before next stage/P overwrite
    }

    // final 1/s exchange (reuse rlds)
    if (lg == 0) rlds[w * 16 + lr] = 1.f / s;
    __syncthreads();
    float inv0 = rlds[lr], inv1 = rlds[16 + lr], inv2 = rlds[32 + lr], inv3 = rlds[48 + lr];
    #pragma unroll
    for (int ct = 0; ct < 8; ++ct) {
        #pragma unroll
        for (int g = 0; g < 4; ++g) {
            float iv = (g == 0) ? inv0 : (g == 1) ? inv1 : (g == 2) ? inv2 : inv3;
            ushort4 o;
            o.x = f2bf(acc[ct][g][0] * iv);
            o.y = f2bf(acc[ct][g][1] * iv);
            o.z = f2bf(acc[ct][g][2] * iv);
            o.w = f2bf(acc[ct][g][3] * iv);
            *(ushort4*)(O + (size_t)batch * (4096*512) + (size_t)(i0 + g*16 + lr) * 512
                        + w * 128 + ct * 16 + lg * 4) = o;
        }
    }
}

// ---------------- final projection + bias + residual (fp32 out)
__global__ __launch_bounds__(256) void proj_kernel(const ushort_t* __restrict__ O, const ushort_t* __restrict__ wt,
                          const float* __restrict__ bp, const float* __restrict__ x, float* __restrict__ out) {
    int wid = threadIdx.x >> 6, lane = threadIdx.x & 63;
    int lr = lane & 15, lg = lane >> 4;
    int r0 = blockIdx.x * 64 + wid * 16;
    int c0 = blockIdx.y * 64;
    const ushort_t* W = wt + (size_t)3 * 262144;
    const ushort_t* arow = O + (size_t)(r0 + lr) * 512 + lg * 8;
    f32x4 acc[4] = {};
    for (int k0 = 0; k0 < 512; k0 += 32) {
        s16x8 af = *(const s16x8*)(arow + k0);
        #pragma unroll
        for (int ct = 0; ct < 4; ++ct) {
            s16x8 bf = *(const s16x8*)(W + (size_t)(c0 + ct*16 + lr) * 512 + k0 + lg * 8);
            acc[ct] = __builtin_amdgcn_mfma_f32_16x16x32_bf16(af, bf, acc[ct], 0, 0, 0);
        }
    }
    #pragma unroll
    for (int ct = 0; ct < 4; ++ct) {
        int cg = c0 + ct*16 + lr;
        float bb = bp[cg];
        #pragma unroll
        for (int r2 = 0; r2 < 4; ++r2) {
            size_t idx = (size_t)(r0 + lg*4 + r2) * 512 + cg;
            out[idx] = acc[ct][r2] + bb + x[idx];
        }
    }
}

extern "C" void kernel_launch(void* const* d_in, const int* in_sizes, int n_in,
                              void* d_out, int out_size, void* d_ws, size_t ws_size,
                              hipStream_t stream) {
    (void)in_sizes; (void)n_in; (void)out_size; (void)ws_size;
    const float* x     = (const float*)d_in[0];
    const float* gamma = (const float*)d_in[1];
    const float* beta  = (const float*)d_in[2];
    const float* wq    = (const float*)d_in[3];
    const float* bq    = (const float*)d_in[4];
    const float* wk    = (const float*)d_in[5];
    const float* bk    = (const float*)d_in[6];
    const float* wv    = (const float*)d_in[7];
    const float* bv    = (const float*)d_in[8];
    const float* wp    = (const float*)d_in[9];
    const float* bp    = (const float*)d_in[10];
    float* out = (float*)d_out;

    char* ws = (char*)d_ws;
    ushort_t* wt   = (ushort_t*)(ws);                 // 2 MB  (4x 512x512 bf16, transposed)
    float*    stats= (float*)(ws + (2ull<<20));       // 1 KB
    ushort_t* xn   = (ushort_t*)(ws + (4ull<<20));    // 16 MB
    ushort_t* qb   = (ushort_t*)(ws + (20ull<<20));   // 16 MB (pre-scaled by C^-0.5)
    ushort_t* kb   = (ushort_t*)(ws + (36ull<<20));   // 16 MB
    ushort_t* vt   = (ushort_t*)(ws + (52ull<<20));   // 16 MB ([b][c][n] transposed)
    ushort_t* Ob   = (ushort_t*)(ws + (68ull<<20));   // 16 MB

    hipLaunchKernelGGL(wconv_kernel,    dim3(4096),       dim3(256), 0, stream, wq, wk, wv, wp, wt);
    hipLaunchKernelGGL(gn_stats_kernel, dim3(128),        dim3(256), 0, stream, x, stats);
    hipLaunchKernelGGL(gn_norm_kernel,  dim3(8192),       dim3(256), 0, stream, x, gamma, beta, stats, xn);
    hipLaunchKernelGGL(qkv_kernel,      dim3(256, 8, 3),  dim3(256), 0, stream, xn, wt, bq, bk, bv, qb, kb, vt);
    hipLaunchKernelGGL(attn_kernel,     dim3(64, 4),      dim3(256), 0, stream, qb, kb, vt, Ob);
    hipLaunchKernelGGL(proj_kernel,     dim3(256, 8),     dim3(256), 0, stream, Ob, wt, bp, x, out);
}